// Round 16
// baseline (153.863 us; speedup 1.0000x reference)
//
#include <hip/hip_runtime.h>
#include <hip/hip_bf16.h>
#include <math.h>

#define G_ 64
#define NEG_SLOPE 0.2f
#define EPS_ 1e-5f
#define BBITS 7
#define BSZ 128    // nodes per bucket
#define CAP 2048   // max edges per bucket (mean ~1280, huge margin)
#define EPB 2048   // edges per block in bucket role (489 blocks)

typedef __attribute__((ext_vector_type(8))) unsigned short ushort8;
typedef __attribute__((ext_vector_type(8))) short bf16x8;
typedef __attribute__((ext_vector_type(4))) float f32x4;

#define DPP_ADD(t, ctrl)                                                   \
  do {                                                                     \
    int _p = __builtin_amdgcn_update_dpp(0, __float_as_int(t), (ctrl),     \
                                         0xf, 0xf, true);                  \
    (t) += __int_as_float(_p);                                             \
  } while (0)
// 8-lane (per-head, packed dims) sum: xor1, xor2, half-mirror.
#define REDUCE8(t)                                                         \
  do {                                                                     \
    DPP_ADD(t, 0xB1);                                                      \
    DPP_ADD(t, 0x4E);                                                      \
    DPP_ADD(t, 0x141);                                                     \
  } while (0)

__device__ __forceinline__ float leaky_(float e) {
  return 0.6f * e + 0.4f * fabsf(e);  // == e>=0 ? e : 0.2e
}

__device__ __forceinline__ short f2bf(float f) {
  __hip_bfloat16 h = __float2bfloat16(f);
  return *reinterpret_cast<short*>(&h);
}

// ---------------- K0: init — prepack W frags + zero scratch --------
__global__ __launch_bounds__(256) void init_kernel(
    const float* __restrict__ Wl, const float* __restrict__ Wr,
    bf16x8* __restrict__ bpack, int* __restrict__ bcnt,
    float* __restrict__ gzero, int nb) {
  if (blockIdx.x == 0) {
    const int lane = threadIdx.x;
    if (lane < 64) {
      const int lrow = lane & 15;
      const int lgrp = lane >> 4;
#pragma unroll
      for (int ct = 0; ct < 8; ++ct) {
        const float* W = (ct < 4) ? Wl : Wr;
        const int col = ((ct & 3) * 16) + lrow;
#pragma unroll
        for (int kk = 0; kk < 2; ++kk) {
          const int kb = kk * 32 + lgrp * 8;
          bf16x8 f;
#pragma unroll
          for (int j = 0; j < 8; ++j) f[j] = f2bf(W[(kb + j) * 64 + col]);
          bpack[(ct * 2 + kk) * 64 + lane] = f;
        }
      }
    }
  } else {
    const int idx = (blockIdx.x - 1) * 256 + threadIdx.x;
    const int stride = (gridDim.x - 1) * 256;
    for (int j = idx; j < nb; j += stride) bcnt[j] = 0;
    for (int j = idx; j < 2 * G_ * 64 + G_; j += stride) gzero[j] = 0.f;
  }
}

// ---------------- K1: fused proj (MFMA) ∥ bucket sort --------------
// proj and bucket are data-independent; one launch with a block-role
// split lets their complementary pipes (MFMA+stores vs atomics+LDS)
// co-reside instead of serializing. Bucket blocks first in dispatch.
__global__ __launch_bounds__(256) void projbucket_kernel(
    const float* __restrict__ x, const bf16x8* __restrict__ bpack,
    __hip_bfloat16* __restrict__ xlb, __hip_bfloat16* __restrict__ xrb,
    const int* __restrict__ esrc, const int* __restrict__ edst,
    int* __restrict__ bcnt, unsigned int* __restrict__ packed,
    int n, int e, int nb, int nbucket) {
  __shared__ int cnt[800];
  __shared__ int base[800];
  if ((int)blockIdx.x < nbucket) {
    // ---- bucket role (R15-proven: reg-cached edges, one read pass) ----
    const int t = threadIdx.x;
    const int e0 = blockIdx.x * EPB;
    const int e1 = (e0 + EPB) < e ? (e0 + EPB) : e;
    int dloc[8], sloc[8];
#pragma unroll
    for (int it = 0; it < 8; ++it) {
      const int i = e0 + t + it * 256;
      const bool ok = i < e1;
      dloc[it] = ok ? edst[i] : -1;
      sloc[it] = ok ? esrc[i] : 0;
    }
    for (int b = t; b < nb; b += 256) cnt[b] = 0;
    __syncthreads();
#pragma unroll
    for (int it = 0; it < 8; ++it)
      if (dloc[it] >= 0) atomicAdd(&cnt[dloc[it] >> BBITS], 1);
    __syncthreads();
    for (int b = t; b < nb; b += 256) {
      int c = cnt[b];
      base[b] = c ? atomicAdd(&bcnt[b], c) : 0;
      cnt[b] = 0;  // reuse as cursor
    }
    __syncthreads();
#pragma unroll
    for (int it = 0; it < 8; ++it) {
      if (dloc[it] >= 0) {
        const int d = dloc[it];
        const int b = d >> BBITS;
        const int pos = base[b] + atomicAdd(&cnt[b], 1);
        if (pos < CAP)
          packed[(size_t)b * CAP + pos] =
              ((unsigned)(d & (BSZ - 1)) << 17) | (unsigned)sloc[it];
      }
    }
  } else {
    // ---- proj role (R12-proven MFMA projection) ----
    const int lane = threadIdx.x & 63;
    const int wv = threadIdx.x >> 6;
    const int rbase = (blockIdx.x - nbucket) * 64 + wv * 16;
    const int lrow = lane & 15;
    const int lgrp = lane >> 4;

    bf16x8 bfrag[8][2];
#pragma unroll
    for (int ct = 0; ct < 8; ++ct)
#pragma unroll
      for (int kk = 0; kk < 2; ++kk)
        bfrag[ct][kk] = bpack[(ct * 2 + kk) * 64 + lane];

    bf16x8 afrag[2];
    const int r = rbase + lrow;
#pragma unroll
    for (int kk = 0; kk < 2; ++kk) {
      bf16x8 f;
      if (r < n) {
        const float4* p =
            (const float4*)(x + (size_t)r * 64 + kk * 32 + lgrp * 8);
        float4 u = p[0], v = p[1];
        f[0] = f2bf(u.x); f[1] = f2bf(u.y); f[2] = f2bf(u.z); f[3] = f2bf(u.w);
        f[4] = f2bf(v.x); f[5] = f2bf(v.y); f[6] = f2bf(v.z); f[7] = f2bf(v.w);
      } else {
        f = bf16x8{0, 0, 0, 0, 0, 0, 0, 0};
      }
      afrag[kk] = f;
    }

    f32x4 acc[8];
#pragma unroll
    for (int ct = 0; ct < 8; ++ct) acc[ct] = f32x4{0.f, 0.f, 0.f, 0.f};
#pragma unroll
    for (int ct = 0; ct < 8; ++ct)
#pragma unroll
      for (int kk = 0; kk < 2; ++kk)
        acc[ct] = __builtin_amdgcn_mfma_f32_16x16x32_bf16(
            afrag[kk], bfrag[ct][kk], acc[ct], 0, 0, 0);

#pragma unroll
    for (int ct = 0; ct < 8; ++ct) {
      __hip_bfloat16* dst = (ct < 4) ? xlb : xrb;
      const int c = ((ct & 3) * 16) + lrow;
#pragma unroll
      for (int j = 0; j < 4; ++j) {
        const int rr = rbase + lgrp * 4 + j;
        if (rr < n) dst[(size_t)rr * 64 + c] = __float2bfloat16(acc[ct][j]);
      }
    }
  }
}

// ---------------- K3: per-bucket LDS counting sort -----------------
__global__ __launch_bounds__(256) void sort_kernel(
    unsigned int* __restrict__ packed, const int* __restrict__ bcnt,
    int2* __restrict__ nse, int n) {
  __shared__ unsigned int stage[CAP];
  __shared__ int cnt[BSZ];
  __shared__ int sc[BSZ];
  __shared__ int off[BSZ + 1];
  const int t = threadIdx.x;
  const int b = blockIdx.x;
  int ecnt = bcnt[b];
  if (ecnt > CAP) ecnt = CAP;
  for (int j = t; j < ecnt; j += 256) stage[j] = packed[(size_t)b * CAP + j];
  if (t < BSZ) cnt[t] = 0;
  __syncthreads();
  for (int j = t; j < ecnt; j += 256) atomicAdd(&cnt[stage[j] >> 17], 1);
  __syncthreads();
  if (t < BSZ) sc[t] = cnt[t];
  __syncthreads();
#pragma unroll
  for (int o = 1; o < BSZ; o <<= 1) {
    int v = 0;
    if (t < BSZ && t >= o) v = sc[t - o];
    __syncthreads();
    if (t < BSZ) sc[t] += v;
    __syncthreads();
  }
  if (t < BSZ) {
    off[t + 1] = sc[t];
    if (t == 0) off[0] = 0;
    cnt[t] = sc[t] - cnt[t];  // exclusive prefix = scatter cursor
  }
  __syncthreads();
  for (int j = t; j < ecnt; j += 256) {
    unsigned v = stage[j];
    int pos = atomicAdd(&cnt[v >> 17], 1);
    packed[(size_t)b * CAP + pos] = v & 0x1FFFF;  // sorted src id
  }
  const int nodebase = b << BBITS;
  if (t < BSZ && nodebase + t < n) {
    int s = off[t];
    nse[nodebase + t] = make_int2(b * CAP + s, off[t + 1] - s);
  }
}

// ---------------- K4: aggregate — packed dword, bursted loads ------
// (R12 proven form: 1 node/wave, two-tier 4/8-load burst, ~56.6us.)
template <int NB>
__device__ __forceinline__ void burst_(
    const char* xbase, unsigned poff, int myedge, int half, int tot,
    float xr0, float xr1, float a0, float a1,
    float& acc0, float& acc1, float& den) {
  unsigned vv[NB];
#pragma unroll
  for (int j = 0; j < NB; ++j) {
    const int sa = __builtin_amdgcn_readlane(myedge, 2 * j);
    const int sb = __builtin_amdgcn_readlane(myedge, 2 * j + 1);
    const int s = half ? sb : sa;
    vv[j] = *(const unsigned*)(xbase + (((unsigned)s << 7) | poff));
  }
#pragma unroll
  for (int j = 0; j < NB; ++j) {
    const unsigned v = vv[j];
    const float l0 = __uint_as_float(v << 16);
    const float l1 = __uint_as_float(v & 0xFFFF0000u);
    float e0 = leaky_(l0 + xr0);
    float e1 = leaky_(l1 + xr1);
    float t = a0 * e0 + a1 * e1;
    REDUCE8(t);
    float p = exp2f(t);
    p = ((2 * j + half) < tot) ? p : 0.f;
    acc0 = fmaf(p, l0, acc0);
    acc1 = fmaf(p, l1, acc1);
    den += p;
  }
}

__global__ __launch_bounds__(256) void aggregate_kernel(
    const __hip_bfloat16* __restrict__ xlb,
    const __hip_bfloat16* __restrict__ xrb, const float* __restrict__ x,
    const float* __restrict__ att, const float* __restrict__ bias_gat,
    const int2* __restrict__ nse, const unsigned int* __restrict__ srt,
    __hip_bfloat16* __restrict__ hb, int n) {
  const int lane = threadIdx.x & 63;
  const int i = (blockIdx.x * blockDim.x + threadIdx.x) >> 6;
  if (i >= n) return;
  const int pos = lane & 31;
  const int half = lane >> 5;
  const float2 attp = ((const float2*)att)[pos];
  const float a0 = attp.x * 1.44269504f;  // log2(e)
  const float a1 = attp.y * 1.44269504f;
  const unsigned xr_pk = ((const unsigned*)(xrb + (size_t)i * 64))[pos];
  const float xr0 = __uint_as_float(xr_pk << 16);
  const float xr1 = __uint_as_float(xr_pk & 0xFFFF0000u);
  int2 sd = nse[i];
  const int s0 = __builtin_amdgcn_readfirstlane(sd.x);
  const int deg = __builtin_amdgcn_readfirstlane(sd.y);
  const int tot = deg + 1;  // slot 0 = self-loop
  int myedge = i;           // default: self row (also the invalid-slot dummy)
  if (lane > 0 && lane < tot) myedge = (int)srt[s0 + lane - 1];
  float acc0 = 0.f, acc1 = 0.f, den = 0.f;
  const char* xbase = (const char*)xlb;
  const unsigned poff = (unsigned)pos << 2;

  if (tot <= 8) {
    burst_<4>(xbase, poff, myedge, half, tot, xr0, xr1, a0, a1,
              acc0, acc1, den);
  } else {
    burst_<8>(xbase, poff, myedge, half, tot, xr0, xr1, a0, a1,
              acc0, acc1, den);
    // ---- tail pairs (tot > 16; P ~ 5%) ----
    const int kmax = tot < 64 ? tot : 64;
    for (int k = 16; k < kmax; k += 2) {
      const int sa = __builtin_amdgcn_readlane(myedge, k);
      const int sb = (k + 1 < kmax) ? __builtin_amdgcn_readlane(myedge, k + 1)
                                    : sa;
      const int s = half ? sb : sa;
      const unsigned v = *(const unsigned*)(xbase + (((unsigned)s << 7) | poff));
      const float l0 = __uint_as_float(v << 16);
      const float l1 = __uint_as_float(v & 0xFFFF0000u);
      float e0 = leaky_(l0 + xr0);
      float e1 = leaky_(l1 + xr1);
      float t = a0 * e0 + a1 * e1;
      REDUCE8(t);
      float p = exp2f(t);
      p = ((k + half) < kmax) ? p : 0.f;
      acc0 = fmaf(p, l0, acc0);
      acc1 = fmaf(p, l1, acc1);
      den += p;
    }
    for (int kk = 64; kk < tot; ++kk) {  // essentially never
      const int s = (int)srt[s0 + kk - 1];
      const unsigned v = *(const unsigned*)(xbase + (((unsigned)s << 7) | poff));
      const float l0 = __uint_as_float(v << 16);
      const float l1 = __uint_as_float(v & 0xFFFF0000u);
      float e0 = leaky_(l0 + xr0);
      float e1 = leaky_(l1 + xr1);
      float t = a0 * e0 + a1 * e1;
      REDUCE8(t);
      float p = exp2f(t);
      p = half ? 0.f : p;  // count once
      acc0 = fmaf(p, l0, acc0);
      acc1 = fmaf(p, l1, acc1);
      den += p;
    }
  }

  acc0 += __shfl_xor(acc0, 32);
  acc1 += __shfl_xor(acc1, 32);
  den += __shfl_xor(den, 32);
  if (half == 0) {
    const float inv = 1.f / den;
    const float2 xres = ((const float2*)(x + (size_t)i * 64))[pos];
    const float2 bb = ((const float2*)bias_gat)[pos];
    float h0 = fmaf(acc0, inv, bb.x) + xres.x;
    float h1 = fmaf(acc1, inv, bb.y) + xres.y;
    h0 = h0 > 0.f ? h0 : expm1f(h0);
    h1 = h1 > 0.f ? h1 : expm1f(h1);
    __hip_bfloat16 b0 = __float2bfloat16(h0);
    __hip_bfloat16 b1 = __float2bfloat16(h1);
    unsigned pk = ((unsigned)(*(unsigned short*)&b1) << 16) |
                  (unsigned)(*(unsigned short*)&b0);
    ((unsigned*)(hb + (size_t)i * 64))[pos] = pk;
  }
}

// ---------------- K5: graph sum + sumsq (R12-proven form) ----------
// Per-lane u16 loads, wave-uniform batch[i] broadcast, 2 atomics/lane/run.
// (R14's dword row-pair variant stalled on same-address atomic collisions
// + dependent-load serialization: 67us. Do not repeat.)
__global__ __launch_bounds__(256) void gsum2_kernel(
    const __hip_bfloat16* __restrict__ h, const int* __restrict__ batch,
    float* __restrict__ gsum, float* __restrict__ gsq,
    float* __restrict__ gcnt, int n) {
  const int lane = threadIdx.x & 63;
  const int wave = (blockIdx.x * blockDim.x + threadIdx.x) >> 6;
  const int nwaves = (gridDim.x * blockDim.x) >> 6;
  const int chunk = (n + nwaves - 1) / nwaves;
  const int start = wave * chunk;
  const int end = (start + chunk) < n ? (start + chunk) : n;
  float s1 = 0.f, s2 = 0.f, cntl = 0.f;
  int curg = -1;
  for (int i = start; i < end; ++i) {
    int g = batch[i];
    if (g != curg) {
      if (curg >= 0) {
        atomicAdd(&gsum[curg * 64 + lane], s1);
        atomicAdd(&gsq[curg * 64 + lane], s2);
        if (lane == 0) atomicAdd(&gcnt[curg], cntl);
      }
      curg = g; s1 = 0.f; s2 = 0.f; cntl = 0.f;
    }
    float hv = __bfloat162float(h[(size_t)i * 64 + lane]);
    s1 += hv;
    s2 += hv * hv;
    cntl += 1.f;
  }
  if (curg >= 0) {
    atomicAdd(&gsum[curg * 64 + lane], s1);
    atomicAdd(&gsq[curg * 64 + lane], s2);
    if (lane == 0) atomicAdd(&gcnt[curg], cntl);
  }
}

// ---------------- K6: final normalize (stats inline, vectorized) ---
__global__ __launch_bounds__(256) void out_kernel(
    const __hip_bfloat16* __restrict__ hb, const int* __restrict__ batch,
    const float* __restrict__ gsum, const float* __restrict__ gsq,
    const float* __restrict__ gcnt, const float* __restrict__ mscale,
    const float* __restrict__ w, const float* __restrict__ bias,
    float* __restrict__ out, int n) {
  const int total8 = n * 8;  // 8 bf16 per thread
  for (int idx = blockIdx.x * blockDim.x + threadIdx.x; idx < total8;
       idx += gridDim.x * blockDim.x) {
    int i = idx >> 3, q = idx & 7;
    int g = batch[i];
    float c = gcnt[g];
    c = c > 1.f ? c : 1.f;
    float inv = 1.f / c;
    int base = g * 64 + q * 8;
    ushort8 hv8 = ((const ushort8*)hb)[idx];
    float r[8];
#pragma unroll
    for (int j = 0; j < 8; ++j) {
      int dd = q * 8 + j;
      float mean = gsum[base + j] * inv;
      float ms = mscale[dd];
      float var = gsq[base + j] * inv - ms * (2.f - ms) * mean * mean;
      float f = __uint_as_float(((unsigned)hv8[j]) << 16);
      r[j] = (f - ms * mean) * (w[dd] * rsqrtf(var + EPS_)) + bias[dd];
    }
    float4 o0 = make_float4(r[0], r[1], r[2], r[3]);
    float4 o1 = make_float4(r[4], r[5], r[6], r[7]);
    ((float4*)out)[idx * 2] = o0;
    ((float4*)out)[idx * 2 + 1] = o1;
  }
}

extern "C" void kernel_launch(void* const* d_in, const int* in_sizes, int n_in,
                              void* d_out, int out_size, void* d_ws, size_t ws_size,
                              hipStream_t stream) {
  const float* x        = (const float*)d_in[0];
  const int*   eidx     = (const int*)d_in[1];
  const int*   batch    = (const int*)d_in[2];
  const float* Wl       = (const float*)d_in[3];
  const float* Wr       = (const float*)d_in[4];
  const float* att      = (const float*)d_in[5];
  const float* bias_gat = (const float*)d_in[6];
  const float* gw       = (const float*)d_in[7];
  const float* gb       = (const float*)d_in[8];
  const float* gms      = (const float*)d_in[9];
  const int N = in_sizes[0] / 64;
  const int E = in_sizes[1] / 2;
  const int* esrc = eidx;
  const int* edst = eidx + E;
  float* out = (float*)d_out;
  const int NB_ = (N + BSZ - 1) >> BBITS;

  // workspace layout — gsum, gsq, gcnt contiguous (zeroed every call by
  // init_kernel: graph-replay safety). All state rebuilt per call.
  char* wsp = (char*)d_ws;
  float* gsum   = (float*)wsp;                wsp += G_ * 64 * 4;
  float* gsq    = (float*)wsp;                wsp += G_ * 64 * 4;
  float* gcnt   = (float*)wsp;                wsp += G_ * 4;
  bf16x8* bpack = (bf16x8*)wsp;               wsp += 16 * 64 * 16;
  int*   bcnt   = (int*)wsp;                  wsp += (size_t)NB_ * 4;
  int2*  nse    = (int2*)wsp;                 wsp += (size_t)N * 8;
  unsigned int* packed = (unsigned int*)wsp;  wsp += (size_t)NB_ * CAP * 4;
  __hip_bfloat16* xlb = (__hip_bfloat16*)wsp; wsp += (size_t)N * 64 * 2;
  __hip_bfloat16* xrb = (__hip_bfloat16*)wsp; wsp += (size_t)N * 64 * 2;
  __hip_bfloat16* hb  = (__hip_bfloat16*)wsp; wsp += (size_t)N * 64 * 2;

  init_kernel<<<9, 256, 0, stream>>>(Wl, Wr, bpack, bcnt, gsum, NB_);

  const int nbucket = (E + EPB - 1) / EPB;
  const int nproj = (N + 63) / 64;
  projbucket_kernel<<<nbucket + nproj, 256, 0, stream>>>(
      x, bpack, xlb, xrb, esrc, edst, bcnt, packed, N, E, NB_, nbucket);

  sort_kernel<<<NB_, 256, 0, stream>>>(packed, bcnt, nse, N);

  aggregate_kernel<<<(N + 3) / 4, 256, 0, stream>>>(
      xlb, xrb, x, att, bias_gat, nse, packed, hb, N);

  gsum2_kernel<<<1024, 256, 0, stream>>>(hb, batch, gsum, gsq, gcnt, N);
  out_kernel<<<3125, 256, 0, stream>>>(hb, batch, gsum, gsq, gcnt, gms, gw,
                                       gb, out, N);
}

// Round 17
// 150.558 us; speedup vs baseline: 1.0220x; 1.0220x over previous
//
#include <hip/hip_runtime.h>
#include <hip/hip_bf16.h>
#include <math.h>

#define G_ 64
#define NEG_SLOPE 0.2f
#define EPS_ 1e-5f
#define BBITS 7
#define BSZ 128    // nodes per bucket
#define CAP 2048   // max edges per bucket (mean ~1280, huge margin)
#define EPB 2048   // edges per block in bucket role (489 blocks)

typedef __attribute__((ext_vector_type(8))) unsigned short ushort8;
typedef __attribute__((ext_vector_type(8))) short bf16x8;
typedef __attribute__((ext_vector_type(4))) float f32x4;

#define DPP_ADD(t, ctrl)                                                   \
  do {                                                                     \
    int _p = __builtin_amdgcn_update_dpp(0, __float_as_int(t), (ctrl),     \
                                         0xf, 0xf, true);                  \
    (t) += __int_as_float(_p);                                             \
  } while (0)
// 8-lane (per-head, packed dims) sum: xor1, xor2, half-mirror.
#define REDUCE8(t)                                                         \
  do {                                                                     \
    DPP_ADD(t, 0xB1);                                                      \
    DPP_ADD(t, 0x4E);                                                      \
    DPP_ADD(t, 0x141);                                                     \
  } while (0)

__device__ __forceinline__ float leaky_(float e) {
  return 0.6f * e + 0.4f * fabsf(e);  // == e>=0 ? e : 0.2e
}

__device__ __forceinline__ short f2bf(float f) {
  __hip_bfloat16 h = __float2bfloat16(f);
  return *reinterpret_cast<short*>(&h);
}

// ---------------- K0: init — prepack W frags + zero scratch --------
__global__ __launch_bounds__(256) void init_kernel(
    const float* __restrict__ Wl, const float* __restrict__ Wr,
    bf16x8* __restrict__ bpack, int* __restrict__ bcnt,
    float* __restrict__ gzero, int nb) {
  if (blockIdx.x == 0) {
    const int lane = threadIdx.x;
    if (lane < 64) {
      const int lrow = lane & 15;
      const int lgrp = lane >> 4;
#pragma unroll
      for (int ct = 0; ct < 8; ++ct) {
        const float* W = (ct < 4) ? Wl : Wr;
        const int col = ((ct & 3) * 16) + lrow;
#pragma unroll
        for (int kk = 0; kk < 2; ++kk) {
          const int kb = kk * 32 + lgrp * 8;
          bf16x8 f;
#pragma unroll
          for (int j = 0; j < 8; ++j) f[j] = f2bf(W[(kb + j) * 64 + col]);
          bpack[(ct * 2 + kk) * 64 + lane] = f;
        }
      }
    }
  } else {
    const int idx = (blockIdx.x - 1) * 256 + threadIdx.x;
    const int stride = (gridDim.x - 1) * 256;
    for (int j = idx; j < nb; j += stride) bcnt[j] = 0;
    for (int j = idx; j < 2 * G_ * 64 + G_; j += stride) gzero[j] = 0.f;
  }
}

// ---------------- K1: single-pass coarse bucket sort ---------------
// (R15-proven: reg-cached edges, one read pass.)
__global__ __launch_bounds__(256) void bucket_kernel(
    const int* __restrict__ esrc, const int* __restrict__ edst,
    int* __restrict__ bcnt, unsigned int* __restrict__ packed,
    int e, int nb) {
  __shared__ int cnt[800];
  __shared__ int base[800];
  const int t = threadIdx.x;
  const int e0 = blockIdx.x * EPB;
  const int e1 = (e0 + EPB) < e ? (e0 + EPB) : e;
  int dloc[8], sloc[8];
#pragma unroll
  for (int it = 0; it < 8; ++it) {
    const int i = e0 + t + it * 256;
    const bool ok = i < e1;
    dloc[it] = ok ? edst[i] : -1;
    sloc[it] = ok ? esrc[i] : 0;
  }
  for (int b = t; b < nb; b += 256) cnt[b] = 0;
  __syncthreads();
#pragma unroll
  for (int it = 0; it < 8; ++it)
    if (dloc[it] >= 0) atomicAdd(&cnt[dloc[it] >> BBITS], 1);
  __syncthreads();
  for (int b = t; b < nb; b += 256) {
    int c = cnt[b];
    base[b] = c ? atomicAdd(&bcnt[b], c) : 0;
    cnt[b] = 0;  // reuse as cursor
  }
  __syncthreads();
#pragma unroll
  for (int it = 0; it < 8; ++it) {
    if (dloc[it] >= 0) {
      const int d = dloc[it];
      const int b = d >> BBITS;
      const int pos = base[b] + atomicAdd(&cnt[b], 1);
      if (pos < CAP)
        packed[(size_t)b * CAP + pos] =
            ((unsigned)(d & (BSZ - 1)) << 17) | (unsigned)sloc[it];
    }
  }
}

// ---------------- K2: fused sort ∥ proj ----------------------------
// sort depends only on bucket; proj depends only on init. Fusing them
// overlaps two stages of the dependency chain. Sort blocks dispatch
// first; proj blocks backfill CUs as sort blocks retire.
// proj additionally stores xb = bf16(x) (free: afrag already holds the
// converted values) so aggregate's residual read is half the bytes.
__global__ __launch_bounds__(256) void sortproj_kernel(
    unsigned int* __restrict__ packed, const int* __restrict__ bcnt,
    int2* __restrict__ nse, const float* __restrict__ x,
    const bf16x8* __restrict__ bpack, __hip_bfloat16* __restrict__ xlb,
    __hip_bfloat16* __restrict__ xrb, __hip_bfloat16* __restrict__ xb,
    int n, int nsort) {
  __shared__ unsigned int stage[CAP];
  __shared__ int cnt[BSZ];
  __shared__ int sc[BSZ];
  __shared__ int off[BSZ + 1];
  if ((int)blockIdx.x < nsort) {
    // ---- sort role: per-bucket LDS counting sort (R15-proven) ----
    const int t = threadIdx.x;
    const int b = blockIdx.x;
    int ecnt = bcnt[b];
    if (ecnt > CAP) ecnt = CAP;
    for (int j = t; j < ecnt; j += 256) stage[j] = packed[(size_t)b * CAP + j];
    if (t < BSZ) cnt[t] = 0;
    __syncthreads();
    for (int j = t; j < ecnt; j += 256) atomicAdd(&cnt[stage[j] >> 17], 1);
    __syncthreads();
    if (t < BSZ) sc[t] = cnt[t];
    __syncthreads();
#pragma unroll
    for (int o = 1; o < BSZ; o <<= 1) {
      int v = 0;
      if (t < BSZ && t >= o) v = sc[t - o];
      __syncthreads();
      if (t < BSZ) sc[t] += v;
      __syncthreads();
    }
    if (t < BSZ) {
      off[t + 1] = sc[t];
      if (t == 0) off[0] = 0;
      cnt[t] = sc[t] - cnt[t];  // exclusive prefix = scatter cursor
    }
    __syncthreads();
    for (int j = t; j < ecnt; j += 256) {
      unsigned v = stage[j];
      int pos = atomicAdd(&cnt[v >> 17], 1);
      packed[(size_t)b * CAP + pos] = v & 0x1FFFF;  // sorted src id
    }
    const int nodebase = b << BBITS;
    if (t < BSZ && nodebase + t < n) {
      int s = off[t];
      nse[nodebase + t] = make_int2(b * CAP + s, off[t + 1] - s);
    }
  } else {
    // ---- proj role (R12-proven MFMA projection + xb store) ----
    const int lane = threadIdx.x & 63;
    const int wv = threadIdx.x >> 6;
    const int rbase = (blockIdx.x - nsort) * 64 + wv * 16;
    const int lrow = lane & 15;
    const int lgrp = lane >> 4;

    bf16x8 bfrag[8][2];
#pragma unroll
    for (int ct = 0; ct < 8; ++ct)
#pragma unroll
      for (int kk = 0; kk < 2; ++kk)
        bfrag[ct][kk] = bpack[(ct * 2 + kk) * 64 + lane];

    bf16x8 afrag[2];
    const int r = rbase + lrow;
#pragma unroll
    for (int kk = 0; kk < 2; ++kk) {
      bf16x8 f;
      if (r < n) {
        const float4* p =
            (const float4*)(x + (size_t)r * 64 + kk * 32 + lgrp * 8);
        float4 u = p[0], v = p[1];
        f[0] = f2bf(u.x); f[1] = f2bf(u.y); f[2] = f2bf(u.z); f[3] = f2bf(u.w);
        f[4] = f2bf(v.x); f[5] = f2bf(v.y); f[6] = f2bf(v.z); f[7] = f2bf(v.w);
        // free bf16 copy of x for aggregate's residual read
        *reinterpret_cast<bf16x8*>(xb + (size_t)r * 64 + kk * 32 + lgrp * 8) = f;
      } else {
        f = bf16x8{0, 0, 0, 0, 0, 0, 0, 0};
      }
      afrag[kk] = f;
    }

    f32x4 acc[8];
#pragma unroll
    for (int ct = 0; ct < 8; ++ct) acc[ct] = f32x4{0.f, 0.f, 0.f, 0.f};
#pragma unroll
    for (int ct = 0; ct < 8; ++ct)
#pragma unroll
      for (int kk = 0; kk < 2; ++kk)
        acc[ct] = __builtin_amdgcn_mfma_f32_16x16x32_bf16(
            afrag[kk], bfrag[ct][kk], acc[ct], 0, 0, 0);

#pragma unroll
    for (int ct = 0; ct < 8; ++ct) {
      __hip_bfloat16* dst = (ct < 4) ? xlb : xrb;
      const int c = ((ct & 3) * 16) + lrow;
#pragma unroll
      for (int j = 0; j < 4; ++j) {
        const int rr = rbase + lgrp * 4 + j;
        if (rr < n) dst[(size_t)rr * 64 + c] = __float2bfloat16(acc[ct][j]);
      }
    }
  }
}

// ---------------- K3: aggregate — packed dword, bursted loads ------
// (R12 proven form: 1 node/wave, two-tier 4/8-load burst, ~56.6us.)
// Residual now read from xb (bf16): -12.8 MB of FETCH in this kernel.
template <int NB>
__device__ __forceinline__ void burst_(
    const char* xbase, unsigned poff, int myedge, int half, int tot,
    float xr0, float xr1, float a0, float a1,
    float& acc0, float& acc1, float& den) {
  unsigned vv[NB];
#pragma unroll
  for (int j = 0; j < NB; ++j) {
    const int sa = __builtin_amdgcn_readlane(myedge, 2 * j);
    const int sb = __builtin_amdgcn_readlane(myedge, 2 * j + 1);
    const int s = half ? sb : sa;
    vv[j] = *(const unsigned*)(xbase + (((unsigned)s << 7) | poff));
  }
#pragma unroll
  for (int j = 0; j < NB; ++j) {
    const unsigned v = vv[j];
    const float l0 = __uint_as_float(v << 16);
    const float l1 = __uint_as_float(v & 0xFFFF0000u);
    float e0 = leaky_(l0 + xr0);
    float e1 = leaky_(l1 + xr1);
    float t = a0 * e0 + a1 * e1;
    REDUCE8(t);
    float p = exp2f(t);
    p = ((2 * j + half) < tot) ? p : 0.f;
    acc0 = fmaf(p, l0, acc0);
    acc1 = fmaf(p, l1, acc1);
    den += p;
  }
}

__global__ __launch_bounds__(256) void aggregate_kernel(
    const __hip_bfloat16* __restrict__ xlb,
    const __hip_bfloat16* __restrict__ xrb,
    const __hip_bfloat16* __restrict__ xb, const float* __restrict__ att,
    const float* __restrict__ bias_gat, const int2* __restrict__ nse,
    const unsigned int* __restrict__ srt, __hip_bfloat16* __restrict__ hb,
    int n) {
  const int lane = threadIdx.x & 63;
  const int i = (blockIdx.x * blockDim.x + threadIdx.x) >> 6;
  if (i >= n) return;
  const int pos = lane & 31;
  const int half = lane >> 5;
  const float2 attp = ((const float2*)att)[pos];
  const float a0 = attp.x * 1.44269504f;  // log2(e)
  const float a1 = attp.y * 1.44269504f;
  const unsigned xr_pk = ((const unsigned*)(xrb + (size_t)i * 64))[pos];
  const float xr0 = __uint_as_float(xr_pk << 16);
  const float xr1 = __uint_as_float(xr_pk & 0xFFFF0000u);
  int2 sd = nse[i];
  const int s0 = __builtin_amdgcn_readfirstlane(sd.x);
  const int deg = __builtin_amdgcn_readfirstlane(sd.y);
  const int tot = deg + 1;  // slot 0 = self-loop
  int myedge = i;           // default: self row (also the invalid-slot dummy)
  if (lane > 0 && lane < tot) myedge = (int)srt[s0 + lane - 1];
  float acc0 = 0.f, acc1 = 0.f, den = 0.f;
  const char* xbase = (const char*)xlb;
  const unsigned poff = (unsigned)pos << 2;

  if (tot <= 8) {
    burst_<4>(xbase, poff, myedge, half, tot, xr0, xr1, a0, a1,
              acc0, acc1, den);
  } else {
    burst_<8>(xbase, poff, myedge, half, tot, xr0, xr1, a0, a1,
              acc0, acc1, den);
    // ---- tail pairs (tot > 16; P ~ 5%) ----
    const int kmax = tot < 64 ? tot : 64;
    for (int k = 16; k < kmax; k += 2) {
      const int sa = __builtin_amdgcn_readlane(myedge, k);
      const int sb = (k + 1 < kmax) ? __builtin_amdgcn_readlane(myedge, k + 1)
                                    : sa;
      const int s = half ? sb : sa;
      const unsigned v = *(const unsigned*)(xbase + (((unsigned)s << 7) | poff));
      const float l0 = __uint_as_float(v << 16);
      const float l1 = __uint_as_float(v & 0xFFFF0000u);
      float e0 = leaky_(l0 + xr0);
      float e1 = leaky_(l1 + xr1);
      float t = a0 * e0 + a1 * e1;
      REDUCE8(t);
      float p = exp2f(t);
      p = ((k + half) < kmax) ? p : 0.f;
      acc0 = fmaf(p, l0, acc0);
      acc1 = fmaf(p, l1, acc1);
      den += p;
    }
    for (int kk = 64; kk < tot; ++kk) {  // essentially never
      const int s = (int)srt[s0 + kk - 1];
      const unsigned v = *(const unsigned*)(xbase + (((unsigned)s << 7) | poff));
      const float l0 = __uint_as_float(v << 16);
      const float l1 = __uint_as_float(v & 0xFFFF0000u);
      float e0 = leaky_(l0 + xr0);
      float e1 = leaky_(l1 + xr1);
      float t = a0 * e0 + a1 * e1;
      REDUCE8(t);
      float p = exp2f(t);
      p = half ? 0.f : p;  // count once
      acc0 = fmaf(p, l0, acc0);
      acc1 = fmaf(p, l1, acc1);
      den += p;
    }
  }

  acc0 += __shfl_xor(acc0, 32);
  acc1 += __shfl_xor(acc1, 32);
  den += __shfl_xor(den, 32);
  if (half == 0) {
    const float inv = 1.f / den;
    const unsigned xpk = ((const unsigned*)(xb + (size_t)i * 64))[pos];
    const float xres0 = __uint_as_float(xpk << 16);
    const float xres1 = __uint_as_float(xpk & 0xFFFF0000u);
    const float2 bb = ((const float2*)bias_gat)[pos];
    float h0 = fmaf(acc0, inv, bb.x) + xres0;
    float h1 = fmaf(acc1, inv, bb.y) + xres1;
    h0 = h0 > 0.f ? h0 : expm1f(h0);
    h1 = h1 > 0.f ? h1 : expm1f(h1);
    __hip_bfloat16 b0 = __float2bfloat16(h0);
    __hip_bfloat16 b1 = __float2bfloat16(h1);
    unsigned pk = ((unsigned)(*(unsigned short*)&b1) << 16) |
                  (unsigned)(*(unsigned short*)&b0);
    ((unsigned*)(hb + (size_t)i * 64))[pos] = pk;
  }
}

// ---------------- K4: graph sum + sumsq (R12-proven form) ----------
// Per-lane u16 loads, wave-uniform batch[i] broadcast, 2 atomics/lane/run.
// (R14's dword row-pair variant stalled on same-address atomic collisions
// + dependent-load serialization: 67us. Do not repeat.)
__global__ __launch_bounds__(256) void gsum2_kernel(
    const __hip_bfloat16* __restrict__ h, const int* __restrict__ batch,
    float* __restrict__ gsum, float* __restrict__ gsq,
    float* __restrict__ gcnt, int n) {
  const int lane = threadIdx.x & 63;
  const int wave = (blockIdx.x * blockDim.x + threadIdx.x) >> 6;
  const int nwaves = (gridDim.x * blockDim.x) >> 6;
  const int chunk = (n + nwaves - 1) / nwaves;
  const int start = wave * chunk;
  const int end = (start + chunk) < n ? (start + chunk) : n;
  float s1 = 0.f, s2 = 0.f, cntl = 0.f;
  int curg = -1;
  for (int i = start; i < end; ++i) {
    int g = batch[i];
    if (g != curg) {
      if (curg >= 0) {
        atomicAdd(&gsum[curg * 64 + lane], s1);
        atomicAdd(&gsq[curg * 64 + lane], s2);
        if (lane == 0) atomicAdd(&gcnt[curg], cntl);
      }
      curg = g; s1 = 0.f; s2 = 0.f; cntl = 0.f;
    }
    float hv = __bfloat162float(h[(size_t)i * 64 + lane]);
    s1 += hv;
    s2 += hv * hv;
    cntl += 1.f;
  }
  if (curg >= 0) {
    atomicAdd(&gsum[curg * 64 + lane], s1);
    atomicAdd(&gsq[curg * 64 + lane], s2);
    if (lane == 0) atomicAdd(&gcnt[curg], cntl);
  }
}

// ---------------- K5: final normalize (stats inline, vectorized) ---
__global__ __launch_bounds__(256) void out_kernel(
    const __hip_bfloat16* __restrict__ hb, const int* __restrict__ batch,
    const float* __restrict__ gsum, const float* __restrict__ gsq,
    const float* __restrict__ gcnt, const float* __restrict__ mscale,
    const float* __restrict__ w, const float* __restrict__ bias,
    float* __restrict__ out, int n) {
  const int total8 = n * 8;  // 8 bf16 per thread
  for (int idx = blockIdx.x * blockDim.x + threadIdx.x; idx < total8;
       idx += gridDim.x * blockDim.x) {
    int i = idx >> 3, q = idx & 7;
    int g = batch[i];
    float c = gcnt[g];
    c = c > 1.f ? c : 1.f;
    float inv = 1.f / c;
    int base = g * 64 + q * 8;
    ushort8 hv8 = ((const ushort8*)hb)[idx];
    float r[8];
#pragma unroll
    for (int j = 0; j < 8; ++j) {
      int dd = q * 8 + j;
      float mean = gsum[base + j] * inv;
      float ms = mscale[dd];
      float var = gsq[base + j] * inv - ms * (2.f - ms) * mean * mean;
      float f = __uint_as_float(((unsigned)hv8[j]) << 16);
      r[j] = (f - ms * mean) * (w[dd] * rsqrtf(var + EPS_)) + bias[dd];
    }
    float4 o0 = make_float4(r[0], r[1], r[2], r[3]);
    float4 o1 = make_float4(r[4], r[5], r[6], r[7]);
    ((float4*)out)[idx * 2] = o0;
    ((float4*)out)[idx * 2 + 1] = o1;
  }
}

extern "C" void kernel_launch(void* const* d_in, const int* in_sizes, int n_in,
                              void* d_out, int out_size, void* d_ws, size_t ws_size,
                              hipStream_t stream) {
  const float* x        = (const float*)d_in[0];
  const int*   eidx     = (const int*)d_in[1];
  const int*   batch    = (const int*)d_in[2];
  const float* Wl       = (const float*)d_in[3];
  const float* Wr       = (const float*)d_in[4];
  const float* att      = (const float*)d_in[5];
  const float* bias_gat = (const float*)d_in[6];
  const float* gw       = (const float*)d_in[7];
  const float* gb       = (const float*)d_in[8];
  const float* gms      = (const float*)d_in[9];
  const int N = in_sizes[0] / 64;
  const int E = in_sizes[1] / 2;
  const int* esrc = eidx;
  const int* edst = eidx + E;
  float* out = (float*)d_out;
  const int NB_ = (N + BSZ - 1) >> BBITS;

  // workspace layout — gsum, gsq, gcnt contiguous (zeroed every call by
  // init_kernel: graph-replay safety). All state rebuilt per call.
  char* wsp = (char*)d_ws;
  float* gsum   = (float*)wsp;                wsp += G_ * 64 * 4;
  float* gsq    = (float*)wsp;                wsp += G_ * 64 * 4;
  float* gcnt   = (float*)wsp;                wsp += G_ * 4;
  bf16x8* bpack = (bf16x8*)wsp;               wsp += 16 * 64 * 16;
  int*   bcnt   = (int*)wsp;                  wsp += (size_t)NB_ * 4;
  int2*  nse    = (int2*)wsp;                 wsp += (size_t)N * 8;
  unsigned int* packed = (unsigned int*)wsp;  wsp += (size_t)NB_ * CAP * 4;
  __hip_bfloat16* xlb = (__hip_bfloat16*)wsp; wsp += (size_t)N * 64 * 2;
  __hip_bfloat16* xrb = (__hip_bfloat16*)wsp; wsp += (size_t)N * 64 * 2;
  __hip_bfloat16* xb  = (__hip_bfloat16*)wsp; wsp += (size_t)N * 64 * 2;
  __hip_bfloat16* hb  = (__hip_bfloat16*)wsp; wsp += (size_t)N * 64 * 2;

  init_kernel<<<9, 256, 0, stream>>>(Wl, Wr, bpack, bcnt, gsum, NB_);

  const int nbucket = (E + EPB - 1) / EPB;
  bucket_kernel<<<nbucket, 256, 0, stream>>>(esrc, edst, bcnt, packed, E, NB_);

  const int nproj = (N + 63) / 64;
  sortproj_kernel<<<NB_ + nproj, 256, 0, stream>>>(
      packed, bcnt, nse, x, bpack, xlb, xrb, xb, N, NB_);

  aggregate_kernel<<<(N + 3) / 4, 256, 0, stream>>>(
      xlb, xrb, xb, att, bias_gat, nse, packed, hb, N);

  gsum2_kernel<<<1024, 256, 0, stream>>>(hb, batch, gsum, gsq, gcnt, N);
  out_kernel<<<3125, 256, 0, stream>>>(hb, batch, gsum, gsq, gcnt, gms, gw,
                                       gb, out, N);
}